// Round 1
// baseline (2259.009 us; speedup 1.0000x reference)
//
#include <hip/hip_runtime.h>

// Problem constants
#define BSZ   128
#define NTOK  512
#define SDIM  256
#define PDIM  128
#define FDIM  256
#define NIT   30

// =====================================================================
// K0: transpose W [256,128] -> Wt [128,256]
// =====================================================================
__global__ __launch_bounds__(256) void transpose_w_kernel(const float* __restrict__ W,
                                                          float* __restrict__ Wt) {
    int idx = blockIdx.x * 256 + threadIdx.x;   // [0, 32768)
    int d = idx >> 7;        // 0..255
    int p = idx & 127;       // 0..127
    Wt[p * 256 + d] = W[idx];
}

// =====================================================================
// K1: h = X@W + b -> LayerNorm -> *g+beta -> l2norm.
// X:[65536,256], Wt:[128,256] (col-major of W), out:[65536,128]
// Block: 256 thr, 32 rows/block. Thread: 4 rows (rg+8i) x 4 cols (cg+32j).
// LDS strides 66 (odd*2): b-side bank = 2*cg (2-way, free), a-side broadcast.
// =====================================================================
__global__ __launch_bounds__(256) void proj_kernel(const float* __restrict__ X,
                                                   const float* __restrict__ Wt,
                                                   const float* __restrict__ bias,
                                                   const float* __restrict__ gamma,
                                                   const float* __restrict__ beta,
                                                   float* __restrict__ out) {
    __shared__ float sX[32 * 66];
    __shared__ float sB[128 * 66];
    const int t = threadIdx.x;
    const int row0 = blockIdx.x * 32;
    const int cg = t & 31;      // col group
    const int rg = t >> 5;      // 0..7
    float acc[4][4] = {};

    for (int dc = 0; dc < 4; ++dc) {   // 4 k-chunks of 64
#pragma unroll
        for (int i = 0; i < 2; ++i) {  // stage 32x64 X chunk
            int e = t + 256 * i;
            int r = e >> 4, k4 = (e & 15) * 4;
            float4 v = *(const float4*)&X[(size_t)(row0 + r) * 256 + dc * 64 + k4];
            float* dst = &sX[r * 66 + k4];
            dst[0] = v.x; dst[1] = v.y; dst[2] = v.z; dst[3] = v.w;
        }
#pragma unroll
        for (int i = 0; i < 8; ++i) {  // stage 128x64 W chunk
            int e = t + 256 * i;
            int c = e >> 4, k4 = (e & 15) * 4;
            float4 v = *(const float4*)&Wt[(size_t)c * 256 + dc * 64 + k4];
            float* dst = &sB[c * 66 + k4];
            dst[0] = v.x; dst[1] = v.y; dst[2] = v.z; dst[3] = v.w;
        }
        __syncthreads();
#pragma unroll 8
        for (int kk = 0; kk < 64; kk += 2) {
            float2 a2[4], b2[4];
#pragma unroll
            for (int j = 0; j < 4; ++j) b2[j] = *(const float2*)&sB[(cg + 32 * j) * 66 + kk];
#pragma unroll
            for (int i = 0; i < 4; ++i) a2[i] = *(const float2*)&sX[(rg + 8 * i) * 66 + kk];
#pragma unroll
            for (int i = 0; i < 4; ++i)
#pragma unroll
                for (int j = 0; j < 4; ++j)
                    acc[i][j] += a2[i].x * b2[j].x + a2[i].y * b2[j].y;
        }
        __syncthreads();
    }

    float bia[4], gam[4], bet[4];
#pragma unroll
    for (int j = 0; j < 4; ++j) {
        int c = cg + 32 * j;
        bia[j] = bias[c]; gam[j] = gamma[c]; bet[j] = beta[c];
    }

#pragma unroll
    for (int i = 0; i < 4; ++i) {
        int r = rg + 8 * i;
        float h[4];
        float s1 = 0.f, s2 = 0.f;
#pragma unroll
        for (int j = 0; j < 4; ++j) {
            h[j] = acc[i][j] + bia[j];
            s1 += h[j];
            s2 += h[j] * h[j];
        }
        // reduce across the 32 cg-lanes (wave halves: xor<32 stays inside)
        for (int m = 1; m < 32; m <<= 1) {
            s1 += __shfl_xor(s1, m);
            s2 += __shfl_xor(s2, m);
        }
        float mu  = s1 * (1.f / 128.f);
        float var = s2 * (1.f / 128.f) - mu * mu;
        float rstd = 1.f / sqrtf(var + 1e-5f);
        float y[4]; float s3 = 0.f;
#pragma unroll
        for (int j = 0; j < 4; ++j) {
            y[j] = (h[j] - mu) * rstd * gam[j] + bet[j];
            s3 += y[j] * y[j];
        }
        for (int m = 1; m < 32; m <<= 1) s3 += __shfl_xor(s3, m);
        float inv = 1.f / fmaxf(sqrtf(s3), 1e-12f);
#pragma unroll
        for (int j = 0; j < 4; ++j)
            out[(size_t)(row0 + r) * 128 + cg + 32 * j] = y[j] * inv;
    }
}

// =====================================================================
// K2: K[b,n,m] = exp(-clip(1 - Sp[b,n].Fp[b,m],0,2)/0.1)  -> stored in d_out P region
// grid: (64 tiles of 64x64, 128 batches), block 256, thread 4x4.
// =====================================================================
__global__ __launch_bounds__(256) void cosk_kernel(const float* __restrict__ SP,
                                                   const float* __restrict__ FP,
                                                   float* __restrict__ Kout) {
    const int b = blockIdx.y;
    const int tile = blockIdx.x;
    const int n0 = (tile >> 3) * 64, m0 = (tile & 7) * 64;
    __shared__ float sA[64 * 66];
    __shared__ float sB[64 * 66];
    const float* A  = SP + (size_t)b * NTOK * PDIM;
    const float* Bm = FP + (size_t)b * NTOK * PDIM;
    const int t = threadIdx.x;
    const int mg = t & 15, ng = t >> 4;
    float acc[4][4] = {};

    for (int kc = 0; kc < 2; ++kc) {   // 2 k-chunks of 64 (PDIM=128)
#pragma unroll
        for (int i = 0; i < 4; ++i) {
            int e = t + 256 * i;           // 0..1023
            int r = e >> 4, k4 = (e & 15) * 4;
            float4 va = *(const float4*)&A [(size_t)(n0 + r) * 128 + kc * 64 + k4];
            float4 vb = *(const float4*)&Bm[(size_t)(m0 + r) * 128 + kc * 64 + k4];
            float* da = &sA[r * 66 + k4];
            da[0] = va.x; da[1] = va.y; da[2] = va.z; da[3] = va.w;
            float* db = &sB[r * 66 + k4];
            db[0] = vb.x; db[1] = vb.y; db[2] = vb.z; db[3] = vb.w;
        }
        __syncthreads();
#pragma unroll 8
        for (int kk = 0; kk < 64; kk += 2) {
            float2 a2[4], b2[4];
#pragma unroll
            for (int i = 0; i < 4; ++i) a2[i] = *(const float2*)&sA[(ng + 16 * i) * 66 + kk];
#pragma unroll
            for (int j = 0; j < 4; ++j) b2[j] = *(const float2*)&sB[(mg + 16 * j) * 66 + kk];
#pragma unroll
            for (int i = 0; i < 4; ++i)
#pragma unroll
                for (int j = 0; j < 4; ++j)
                    acc[i][j] += a2[i].x * b2[j].x + a2[i].y * b2[j].y;
        }
        __syncthreads();
    }

#pragma unroll
    for (int i = 0; i < 4; ++i) {
        int n = n0 + ng + 16 * i;
#pragma unroll
        for (int j = 0; j < 4; ++j) {
            int m = m0 + mg + 16 * j;
            float C = fminf(fmaxf(1.f - acc[i][j], 0.f), 2.f);
            Kout[((size_t)b * NTOK + n) * NTOK + m] = expf(-10.f * C);
        }
    }
}

// =====================================================================
// K3: u-update.  block (b, strip s of 64 rows). Recompute v from strip
// partials (v=1 at iter 0), then per row: Kv dot, u = r/(Kv+1e-8) (UNCLIPPED,
// matching reference order; clip applied by consumers of final u).
// =====================================================================
__global__ __launch_bounds__(256) void kv_kernel(const float* __restrict__ Kmat,
                                                 const float* __restrict__ parts,
                                                 float* __restrict__ u, int iter) {
    const int blk = blockIdx.x;
    const int b = blk >> 3, s = blk & 7;
    __shared__ float vs[NTOK];
    const int t = threadIdx.x;
    if (iter == 0) {
        vs[t] = 1.f; vs[t + 256] = 1.f;
    } else {
        for (int m = t; m < NTOK; m += 256) {
            float sum = 0.f;
            const float* pp = parts + (size_t)b * 8 * NTOK + m;
#pragma unroll
            for (int q = 0; q < 8; ++q) sum += pp[q * NTOK];
            float v = (1.f / 512.f) / (sum + 1e-8f);
            vs[m] = fminf(fmaxf(v, 1e-8f), 1e8f);
        }
    }
    __syncthreads();

    const int wave = t >> 6, lane = t & 63;
    float4 v0 = *(const float4*)&vs[4 * lane];
    float4 v1 = *(const float4*)&vs[256 + 4 * lane];
    for (int rr = 0; rr < 16; ++rr) {
        int r = wave * 16 + rr;
        const float* Krow = Kmat + ((size_t)b * NTOK + s * 64 + r) * NTOK;
        float4 k0 = *(const float4*)&Krow[4 * lane];
        float4 k1 = *(const float4*)&Krow[256 + 4 * lane];
        float p = k0.x * v0.x + k0.y * v0.y + k0.z * v0.z + k0.w * v0.w
                + k1.x * v1.x + k1.y * v1.y + k1.z * v1.z + k1.w * v1.w;
        for (int m = 1; m < 64; m <<= 1) p += __shfl_xor(p, m);
        if (lane == 0)
            u[(size_t)b * NTOK + s * 64 + r] = (1.f / 512.f) / (p + 1e-8f);
    }
}

// =====================================================================
// K4: strip-partial column sums  parts[b,s,m] = sum_{n in strip} K[n,m]*u[n]
// (row-major coalesced reads; no atomics).
// =====================================================================
__global__ __launch_bounds__(256) void ktu_kernel(const float* __restrict__ Kmat,
                                                  const float* __restrict__ u,
                                                  float* __restrict__ parts) {
    const int blk = blockIdx.x;
    const int b = blk >> 3, s = blk & 7;
    __shared__ float us[64];
    const int t = threadIdx.x;
    if (t < 64) us[t] = u[(size_t)b * NTOK + s * 64 + t];
    __syncthreads();
    float a0 = 0.f, a1 = 0.f;
    const float* base = Kmat + ((size_t)b * NTOK + s * 64) * NTOK;
#pragma unroll 4
    for (int r = 0; r < 64; ++r) {
        float2 k2 = *(const float2*)&base[(size_t)r * NTOK + 2 * t];
        float ur = us[r];
        a0 += k2.x * ur;
        a1 += k2.y * ur;
    }
    float* pp = parts + ((size_t)(b * 8 + s)) * NTOK + 2 * t;
    pp[0] = a0; pp[1] = a1;
}

// =====================================================================
// K5: final.  v from last partials (clipped), u clipped.  Per strip:
// P = u*K*v written IN-PLACE over K (d_out P region, own strip only),
// staged per 64-m chunk in LDS, then F_tilde strip += P_chunk @ F.
// Thread: 4 F-cols (4*dg) x 16 rows (16*ng+i).
// =====================================================================
__global__ __launch_bounds__(256) void final_kernel(const float* __restrict__ parts,
                                                    const float* __restrict__ u,
                                                    const float* __restrict__ F,
                                                    float* __restrict__ Pout,
                                                    float* __restrict__ FTout) {
    const int blk = blockIdx.x;
    const int b = blk >> 3, s = blk & 7;
    __shared__ float vs[NTOK];
    __shared__ float us[64];
    __shared__ float sP[64 * 68];
    const int t = threadIdx.x;

    for (int m = t; m < NTOK; m += 256) {
        float sum = 0.f;
        const float* pp = parts + (size_t)b * 8 * NTOK + m;
#pragma unroll
        for (int q = 0; q < 8; ++q) sum += pp[q * NTOK];
        float v = (1.f / 512.f) / (sum + 1e-8f);
        vs[m] = fminf(fmaxf(v, 1e-8f), 1e8f);
    }
    if (t < 64) {
        float uu = u[(size_t)b * NTOK + s * 64 + t];
        us[t] = fminf(fmaxf(uu, 1e-8f), 1e8f);
    }
    __syncthreads();

    const int dg = t & 63;   // F cols 4*dg..+4
    const int ng = t >> 6;   // row group: rows 16*ng..+16
    float acc[16][4] = {};
    const float* Fb = F + (size_t)b * NTOK * FDIM;
    float* Pbase = Pout + ((size_t)b * NTOK + s * 64) * NTOK;

    for (int mc = 0; mc < 8; ++mc) {
        // phase 1: P for this 64x64 chunk (in-place over K) + stash in LDS
#pragma unroll
        for (int i = 0; i < 4; ++i) {
            int e = t + 256 * i;            // 0..1023 float4 slots
            int r = e >> 4, m4 = (e & 15) * 4;
            size_t gidx = (size_t)r * NTOK + mc * 64 + m4;
            float4 k4 = *(const float4*)&Pbase[gidx];
            float ur = us[r];
            float4 p4;
            p4.x = k4.x * ur * vs[mc * 64 + m4 + 0];
            p4.y = k4.y * ur * vs[mc * 64 + m4 + 1];
            p4.z = k4.z * ur * vs[mc * 64 + m4 + 2];
            p4.w = k4.w * ur * vs[mc * 64 + m4 + 3];
            *(float4*)&Pbase[gidx] = p4;
            float* dst = &sP[r * 68 + m4];
            dst[0] = p4.x; dst[1] = p4.y; dst[2] = p4.z; dst[3] = p4.w;
        }
        __syncthreads();
        // phase 2: FT[64,256] += P_chunk[64,64] @ F[mchunk,256]
        for (int mm = 0; mm < 64; ++mm) {
            int m = mc * 64 + mm;
            float4 f4 = *(const float4*)&Fb[(size_t)m * FDIM + 4 * dg];
#pragma unroll
            for (int i = 0; i < 16; ++i) {
                float p = sP[(ng * 16 + i) * 68 + mm];
                acc[i][0] += p * f4.x;
                acc[i][1] += p * f4.y;
                acc[i][2] += p * f4.z;
                acc[i][3] += p * f4.w;
            }
        }
        __syncthreads();
    }

#pragma unroll
    for (int i = 0; i < 16; ++i) {
        float4 o;
        o.x = acc[i][0]; o.y = acc[i][1]; o.z = acc[i][2]; o.w = acc[i][3];
        *(float4*)&FTout[((size_t)b * NTOK + s * 64 + ng * 16 + i) * FDIM + 4 * dg] = o;
    }
}

// =====================================================================
extern "C" void kernel_launch(void* const* d_in, const int* in_sizes, int n_in,
                              void* d_out, int out_size, void* d_ws, size_t ws_size,
                              hipStream_t stream) {
    const float* S      = (const float*)d_in[0];
    const float* F      = (const float*)d_in[1];
    const float* W_s    = (const float*)d_in[2];
    const float* b_s    = (const float*)d_in[3];
    const float* g_s    = (const float*)d_in[4];
    const float* beta_s = (const float*)d_in[5];
    const float* W_f    = (const float*)d_in[6];
    const float* b_f    = (const float*)d_in[7];
    const float* g_f    = (const float*)d_in[8];
    const float* beta_f = (const float*)d_in[9];

    float* wsf  = (float*)d_ws;
    float* WT_s = wsf;                       // 32768
    float* WT_f = wsf + 32768;               // 32768
    float* SP   = wsf + 65536;               // 65536*128
    float* FP   = SP + (size_t)65536 * 128;  // 65536*128
    float* U    = FP + (size_t)65536 * 128;  // 65536
    float* PARTS = U + 65536;                // 128*8*512

    float* Pout = (float*)d_out;                      // [128,512,512] (K32 then P, in place)
    float* FT   = Pout + (size_t)BSZ * NTOK * NTOK;   // [128,512,256]

    transpose_w_kernel<<<128, 256, 0, stream>>>(W_s, WT_s);
    transpose_w_kernel<<<128, 256, 0, stream>>>(W_f, WT_f);

    proj_kernel<<<2048, 256, 0, stream>>>(S, WT_s, b_s, g_s, beta_s, SP);
    proj_kernel<<<2048, 256, 0, stream>>>(F, WT_f, b_f, g_f, beta_f, FP);

    cosk_kernel<<<dim3(64, 128), 256, 0, stream>>>(SP, FP, Pout);

    for (int it = 0; it < NIT; ++it) {
        kv_kernel<<<1024, 256, 0, stream>>>(Pout, PARTS, U, it);
        ktu_kernel<<<1024, 256, 0, stream>>>(Pout, U, PARTS);
    }

    final_kernel<<<1024, 256, 0, stream>>>(PARTS, U, F, Pout, FT);
}

// Round 2
// 1548.370 us; speedup vs baseline: 1.4590x; 1.4590x over previous
//
#include <hip/hip_runtime.h>

// Problem constants
#define BSZ   128
#define NTOK  512
#define SDIM  256
#define PDIM  128
#define FDIM  256
#define NIT   30

typedef _Float16 half_t;
typedef _Float16 half8_t __attribute__((ext_vector_type(8)));

// =====================================================================
// K0: transpose W [256,128] -> Wt [128,256]
// =====================================================================
__global__ __launch_bounds__(256) void transpose_w_kernel(const float* __restrict__ W,
                                                          float* __restrict__ Wt) {
    int idx = blockIdx.x * 256 + threadIdx.x;   // [0, 32768)
    int d = idx >> 7;        // 0..255
    int p = idx & 127;       // 0..127
    Wt[p * 256 + d] = W[idx];
}

// =====================================================================
// K1: h = X@W + b -> LayerNorm -> *g+beta -> l2norm.
// X:[65536,256], Wt:[128,256] (col-major of W), out:[65536,128]
// =====================================================================
__global__ __launch_bounds__(256) void proj_kernel(const float* __restrict__ X,
                                                   const float* __restrict__ Wt,
                                                   const float* __restrict__ bias,
                                                   const float* __restrict__ gamma,
                                                   const float* __restrict__ beta,
                                                   float* __restrict__ out) {
    __shared__ float sX[32 * 66];
    __shared__ float sB[128 * 66];
    const int t = threadIdx.x;
    const int row0 = blockIdx.x * 32;
    const int cg = t & 31;      // col group
    const int rg = t >> 5;      // 0..7
    float acc[4][4] = {};

    for (int dc = 0; dc < 4; ++dc) {   // 4 k-chunks of 64
#pragma unroll
        for (int i = 0; i < 2; ++i) {  // stage 32x64 X chunk
            int e = t + 256 * i;
            int r = e >> 4, k4 = (e & 15) * 4;
            float4 v = *(const float4*)&X[(size_t)(row0 + r) * 256 + dc * 64 + k4];
            float* dst = &sX[r * 66 + k4];
            dst[0] = v.x; dst[1] = v.y; dst[2] = v.z; dst[3] = v.w;
        }
#pragma unroll
        for (int i = 0; i < 8; ++i) {  // stage 128x64 W chunk
            int e = t + 256 * i;
            int c = e >> 4, k4 = (e & 15) * 4;
            float4 v = *(const float4*)&Wt[(size_t)c * 256 + dc * 64 + k4];
            float* dst = &sB[c * 66 + k4];
            dst[0] = v.x; dst[1] = v.y; dst[2] = v.z; dst[3] = v.w;
        }
        __syncthreads();
#pragma unroll 8
        for (int kk = 0; kk < 64; kk += 2) {
            float2 a2[4], b2[4];
#pragma unroll
            for (int j = 0; j < 4; ++j) b2[j] = *(const float2*)&sB[(cg + 32 * j) * 66 + kk];
#pragma unroll
            for (int i = 0; i < 4; ++i) a2[i] = *(const float2*)&sX[(rg + 8 * i) * 66 + kk];
#pragma unroll
            for (int i = 0; i < 4; ++i)
#pragma unroll
                for (int j = 0; j < 4; ++j)
                    acc[i][j] += a2[i].x * b2[j].x + a2[i].y * b2[j].y;
        }
        __syncthreads();
    }

    float bia[4], gam[4], bet[4];
#pragma unroll
    for (int j = 0; j < 4; ++j) {
        int c = cg + 32 * j;
        bia[j] = bias[c]; gam[j] = gamma[c]; bet[j] = beta[c];
    }

#pragma unroll
    for (int i = 0; i < 4; ++i) {
        int r = rg + 8 * i;
        float h[4];
        float s1 = 0.f, s2 = 0.f;
#pragma unroll
        for (int j = 0; j < 4; ++j) {
            h[j] = acc[i][j] + bia[j];
            s1 += h[j];
            s2 += h[j] * h[j];
        }
        for (int m = 1; m < 32; m <<= 1) {
            s1 += __shfl_xor(s1, m);
            s2 += __shfl_xor(s2, m);
        }
        float mu  = s1 * (1.f / 128.f);
        float var = s2 * (1.f / 128.f) - mu * mu;
        float rstd = 1.f / sqrtf(var + 1e-5f);
        float y[4]; float s3 = 0.f;
#pragma unroll
        for (int j = 0; j < 4; ++j) {
            y[j] = (h[j] - mu) * rstd * gam[j] + bet[j];
            s3 += y[j] * y[j];
        }
        for (int m = 1; m < 32; m <<= 1) s3 += __shfl_xor(s3, m);
        float inv = 1.f / fmaxf(sqrtf(s3), 1e-12f);
#pragma unroll
        for (int j = 0; j < 4; ++j)
            out[(size_t)(row0 + r) * 128 + cg + 32 * j] = y[j] * inv;
    }
}

// =====================================================================
// K2: K[b,n,m] = exp(-clip(1 - Sp[b,n].Fp[b,m],0,2)/0.1)
//   -> fp32 into d_out P region (read by final_kernel)
//   -> fp16 into d_out FT region (read by sinkhorn passes)
// =====================================================================
__global__ __launch_bounds__(256) void cosk_kernel(const float* __restrict__ SP,
                                                   const float* __restrict__ FP,
                                                   float* __restrict__ Kout,
                                                   half_t* __restrict__ K16out) {
    const int b = blockIdx.y;
    const int tile = blockIdx.x;
    const int n0 = (tile >> 3) * 64, m0 = (tile & 7) * 64;
    __shared__ float sA[64 * 66];
    __shared__ float sB[64 * 66];
    const float* A  = SP + (size_t)b * NTOK * PDIM;
    const float* Bm = FP + (size_t)b * NTOK * PDIM;
    const int t = threadIdx.x;
    const int mg = t & 15, ng = t >> 4;
    float acc[4][4] = {};

    for (int kc = 0; kc < 2; ++kc) {   // 2 k-chunks of 64 (PDIM=128)
#pragma unroll
        for (int i = 0; i < 4; ++i) {
            int e = t + 256 * i;           // 0..1023
            int r = e >> 4, k4 = (e & 15) * 4;
            float4 va = *(const float4*)&A [(size_t)(n0 + r) * 128 + kc * 64 + k4];
            float4 vb = *(const float4*)&Bm[(size_t)(m0 + r) * 128 + kc * 64 + k4];
            float* da = &sA[r * 66 + k4];
            da[0] = va.x; da[1] = va.y; da[2] = va.z; da[3] = va.w;
            float* db = &sB[r * 66 + k4];
            db[0] = vb.x; db[1] = vb.y; db[2] = vb.z; db[3] = vb.w;
        }
        __syncthreads();
#pragma unroll 8
        for (int kk = 0; kk < 64; kk += 2) {
            float2 a2[4], b2[4];
#pragma unroll
            for (int i = 0; i < 4; ++i) a2[i] = *(const float2*)&sA[(ng + 16 * i) * 66 + kk];
#pragma unroll
            for (int j = 0; j < 4; ++j) b2[j] = *(const float2*)&sB[(mg + 16 * j) * 66 + kk];
#pragma unroll
            for (int i = 0; i < 4; ++i)
#pragma unroll
                for (int j = 0; j < 4; ++j)
                    acc[i][j] += a2[i].x * b2[j].x + a2[i].y * b2[j].y;
        }
        __syncthreads();
    }

#pragma unroll
    for (int i = 0; i < 4; ++i) {
        int n = n0 + ng + 16 * i;
#pragma unroll
        for (int j = 0; j < 4; ++j) {
            int m = m0 + mg + 16 * j;
            float C = fminf(fmaxf(1.f - acc[i][j], 0.f), 2.f);
            float K = expf(-10.f * C);
            size_t gidx = ((size_t)b * NTOK + n) * NTOK + m;
            Kout[gidx] = K;
            K16out[gidx] = (half_t)K;
        }
    }
}

// =====================================================================
// K3 (fused Sinkhorn iteration): block = (b, 64-row strip s).
//  A: v from previous iter's strip partials (v=1 at iter 0), clipped.
//  B: per row r (one wave, 16 rows/wave): Kv dot via fp16 row read +
//     wave xor-reduce -> u_r (unclipped, per reference order).
//     Column partials colacc[m] += K[r,m]*u_r accumulated IN THE SAME PASS
//     (lanes already hold their 8 row elements) -> one K read per iter.
//  C: combine 4 waves' column partials in LDS -> parts[b,s,:].
// =====================================================================
__global__ __launch_bounds__(256) void sinkhorn_iter_kernel(const half_t* __restrict__ K16,
                                                            float* __restrict__ parts,
                                                            float* __restrict__ U,
                                                            int iter) {
    const int blk = blockIdx.x;
    const int b = blk >> 3, s = blk & 7;
    __shared__ float vs[NTOK];
    __shared__ float wacc[4][NTOK];
    const int t = threadIdx.x;
    const int wave = t >> 6, lane = t & 63;

    if (iter == 0) {
        vs[t] = 1.f; vs[t + 256] = 1.f;
    } else {
        for (int m = t; m < NTOK; m += 256) {
            float sum = 0.f;
            const float* pp = parts + (size_t)b * 8 * NTOK + m;
#pragma unroll
            for (int q = 0; q < 8; ++q) sum += pp[q * NTOK];
            float v = (1.f / 512.f) / (sum + 1e-8f);
            vs[m] = fminf(fmaxf(v, 1e-8f), 1e8f);
        }
    }
    __syncthreads();

    float vl[8];
#pragma unroll
    for (int j = 0; j < 8; ++j) vl[j] = vs[lane * 8 + j];

    const half_t* Kbase = K16 + ((size_t)b * NTOK + s * 64) * NTOK + lane * 8;
    float colacc[8] = {};
    float ureg = 0.f;

    half8_t kcur = *(const half8_t*)(Kbase + (size_t)(wave * 16) * NTOK);
#pragma unroll
    for (int rr = 0; rr < 16; ++rr) {
        half8_t knext = kcur;
        if (rr < 15) knext = *(const half8_t*)(Kbase + (size_t)(wave * 16 + rr + 1) * NTOK);
        float k[8];
#pragma unroll
        for (int j = 0; j < 8; ++j) k[j] = (float)kcur[j];
        float p = 0.f;
#pragma unroll
        for (int j = 0; j < 8; ++j) p += k[j] * vl[j];
        for (int m = 1; m < 64; m <<= 1) p += __shfl_xor(p, m);
        float u_r = (1.f / 512.f) / (p + 1e-8f);
        if (lane == rr) ureg = u_r;      // lanes 0..15 collect their row's u
#pragma unroll
        for (int j = 0; j < 8; ++j) colacc[j] += k[j] * u_r;
        kcur = knext;
    }
    if (lane < 16) U[(size_t)b * NTOK + s * 64 + wave * 16 + lane] = ureg;

#pragma unroll
    for (int j = 0; j < 8; ++j) wacc[wave][lane * 8 + j] = colacc[j];
    __syncthreads();
    for (int m = t; m < NTOK; m += 256) {
        parts[((size_t)(b * 8 + s)) * NTOK + m] =
            wacc[0][m] + wacc[1][m] + wacc[2][m] + wacc[3][m];
    }
}

// =====================================================================
// K5: final.  v from last partials (clipped), u clipped.  Per strip:
// P = u*K*v written IN-PLACE over K32 (d_out P region, own strip only),
// staged per 64-m chunk in LDS, then F_tilde strip += P_chunk @ F.
// NOTE: FT writes land exactly on this strip's K16 bytes (FT region) --
// K16 is dead after the sinkhorn loop, and final reads only K32.
// =====================================================================
__global__ __launch_bounds__(256) void final_kernel(const float* __restrict__ parts,
                                                    const float* __restrict__ u,
                                                    const float* __restrict__ F,
                                                    float* __restrict__ Pout,
                                                    float* __restrict__ FTout) {
    const int blk = blockIdx.x;
    const int b = blk >> 3, s = blk & 7;
    __shared__ float vs[NTOK];
    __shared__ float us[64];
    __shared__ float sP[64 * 68];
    const int t = threadIdx.x;

    for (int m = t; m < NTOK; m += 256) {
        float sum = 0.f;
        const float* pp = parts + (size_t)b * 8 * NTOK + m;
#pragma unroll
        for (int q = 0; q < 8; ++q) sum += pp[q * NTOK];
        float v = (1.f / 512.f) / (sum + 1e-8f);
        vs[m] = fminf(fmaxf(v, 1e-8f), 1e8f);
    }
    if (t < 64) {
        float uu = u[(size_t)b * NTOK + s * 64 + t];
        us[t] = fminf(fmaxf(uu, 1e-8f), 1e8f);
    }
    __syncthreads();

    const int dg = t & 63;   // F cols 4*dg..+4
    const int ng = t >> 6;   // row group: rows 16*ng..+16
    float acc[16][4] = {};
    const float* Fb = F + (size_t)b * NTOK * FDIM;
    float* Pbase = Pout + ((size_t)b * NTOK + s * 64) * NTOK;

    for (int mc = 0; mc < 8; ++mc) {
        // phase 1: P for this 64x64 chunk (in-place over K32) + stash in LDS
#pragma unroll
        for (int i = 0; i < 4; ++i) {
            int e = t + 256 * i;            // 0..1023 float4 slots
            int r = e >> 4, m4 = (e & 15) * 4;
            size_t gidx = (size_t)r * NTOK + mc * 64 + m4;
            float4 k4 = *(const float4*)&Pbase[gidx];
            float ur = us[r];
            float4 p4;
            p4.x = k4.x * ur * vs[mc * 64 + m4 + 0];
            p4.y = k4.y * ur * vs[mc * 64 + m4 + 1];
            p4.z = k4.z * ur * vs[mc * 64 + m4 + 2];
            p4.w = k4.w * ur * vs[mc * 64 + m4 + 3];
            *(float4*)&Pbase[gidx] = p4;
            float* dst = &sP[r * 68 + m4];
            dst[0] = p4.x; dst[1] = p4.y; dst[2] = p4.z; dst[3] = p4.w;
        }
        __syncthreads();
        // phase 2: FT[64,256] += P_chunk[64,64] @ F[mchunk,256]
        for (int mm = 0; mm < 64; ++mm) {
            int m = mc * 64 + mm;
            float4 f4 = *(const float4*)&Fb[(size_t)m * FDIM + 4 * dg];
#pragma unroll
            for (int i = 0; i < 16; ++i) {
                float p = sP[(ng * 16 + i) * 68 + mm];
                acc[i][0] += p * f4.x;
                acc[i][1] += p * f4.y;
                acc[i][2] += p * f4.z;
                acc[i][3] += p * f4.w;
            }
        }
        __syncthreads();
    }

#pragma unroll
    for (int i = 0; i < 16; ++i) {
        float4 o;
        o.x = acc[i][0]; o.y = acc[i][1]; o.z = acc[i][2]; o.w = acc[i][3];
        *(float4*)&FTout[((size_t)b * NTOK + s * 64 + ng * 16 + i) * FDIM + 4 * dg] = o;
    }
}

// =====================================================================
extern "C" void kernel_launch(void* const* d_in, const int* in_sizes, int n_in,
                              void* d_out, int out_size, void* d_ws, size_t ws_size,
                              hipStream_t stream) {
    const float* S      = (const float*)d_in[0];
    const float* F      = (const float*)d_in[1];
    const float* W_s    = (const float*)d_in[2];
    const float* b_s    = (const float*)d_in[3];
    const float* g_s    = (const float*)d_in[4];
    const float* beta_s = (const float*)d_in[5];
    const float* W_f    = (const float*)d_in[6];
    const float* b_f    = (const float*)d_in[7];
    const float* g_f    = (const float*)d_in[8];
    const float* beta_f = (const float*)d_in[9];

    float* wsf  = (float*)d_ws;
    float* WT_s = wsf;                       // 32768
    float* WT_f = wsf + 32768;               // 32768
    float* SP   = wsf + 65536;               // 65536*128
    float* FP   = SP + (size_t)65536 * 128;  // 65536*128
    float* U    = FP + (size_t)65536 * 128;  // 65536
    float* PARTS = U + 65536;                // 128*8*512

    float* Pout = (float*)d_out;                      // [128,512,512] (K32 then P, in place)
    float* FT   = Pout + (size_t)BSZ * NTOK * NTOK;   // [128,512,256]
    // fp16 K lives in the FT region during the sinkhorn phase:
    // 128*512*512*2 bytes == 128*512*256*4 bytes exactly.
    half_t* K16 = (half_t*)FT;

    transpose_w_kernel<<<128, 256, 0, stream>>>(W_s, WT_s);
    transpose_w_kernel<<<128, 256, 0, stream>>>(W_f, WT_f);

    proj_kernel<<<2048, 256, 0, stream>>>(S, WT_s, b_s, g_s, beta_s, SP);
    proj_kernel<<<2048, 256, 0, stream>>>(F, WT_f, b_f, g_f, beta_f, FP);

    cosk_kernel<<<dim3(64, 128), 256, 0, stream>>>(SP, FP, Pout, K16);

    for (int it = 0; it < NIT; ++it) {
        sinkhorn_iter_kernel<<<1024, 256, 0, stream>>>(K16, PARTS, U, it);
    }

    final_kernel<<<1024, 256, 0, stream>>>(PARTS, U, F, Pout, FT);
}